// Round 7
// baseline (1234.079 us; speedup 1.0000x reference)
//
#include <hip/hip_runtime.h>

#define NXg   128
#define NYg   128
#define NSTA  24
#define NPICK 200000
#define INFV  1.0e6f
#define MAXS  160    // safety cap on sweeps; clean-sweep exit is exact

// raw v_sqrt_f32 (~1 ulp) — skips the IEEE fixup chain
__device__ __forceinline__ float fsqrt_fast(float x) {
#if __has_builtin(__builtin_amdgcn_sqrtf)
  return __builtin_amdgcn_sqrtf(x);
#else
  float r; asm("v_sqrt_f32 %0, %1" : "=v"(r) : "v"(x)); return r;
#endif
}

// Godunov upwind local solver (same float ops/rounding as reference).
// No max(.,0) clamp: in the selected (two-sided) branch |dd|<f so the sqrt
// arg > f^2 > 0; a NaN in the other branch is discarded by the select.
__device__ __forceinline__ float cell_upd(float old, float up, float dn,
                                          float lf, float rt, float f, int& chg)
{
  const float a  = fminf(up, dn);          // min x-neighbors (rows)
  const float b  = fminf(lf, rt);          // min y-neighbors (cols)
  const float dd = a - b;
  const float t2 = (2.0f * f) * f;
  const float s  = __builtin_fmaf(-dd, dd, t2);
  const float tw = 0.5f * ((a + b) + fsqrt_fast(s));
  const float on = fminf(a, b) + f;
  const float cand = (fabsf(dd) >= f) ? on : tw;
  chg |= (cand < old);
  return fminf(old, cand);
}

// ---------------------------------------------------------------------------
// One GLOBAL directional Gauss-Seidel sweep over the 128x128 field in LDS,
// executed by a single wave (64 lanes) with anti-diagonal wavefront order.
// Lane l owns adjacent column pair; at step d it processes virtual row d-l.
// "Behind" neighbors (up = own prev step regs, left = shfl of lane l-1's
// prev-step value) are fresh; "ahead" (down/right, from LDS) are old —
// chaotic relaxation of the monotone min-operator: same fixed point, and a
// clean sweep (no change anywhere) exactly certifies convergence.
// ---------------------------------------------------------------------------
template<int DR, int DC>
__device__ __forceinline__ int gsweep(float* __restrict__ su,
                                      const float* __restrict__ sfh, int lane)
{
  const int cmin = (DC > 0) ? 2 * lane : 126 - 2 * lane;  // lower col of pair
  float prev0 = INFV, prev1 = INFV;   // my pair's values at previous row
  int chg = 0;
  for (int d = 0; d < 191; ++d) {
    // left-behind value for my first cell = lane l-1's second cell, step d-1
    float lfin = __shfl(prev1, lane - 1, 64);
    if (lane == 0) lfin = INFV;
    const int rr = d - lane;                 // virtual row index
    if (rr >= 0 && rr < 128) {
      const int r    = (DR > 0) ? rr : 127 - rr;
      const int rdn  = (DR > 0) ? r + 1 : r - 1;   // "ahead" row (old vals)
      const int base = r * NYg + cmin;
      const float2 oldp = *(const float2*)&su[base];
      const float2 fhp  = *(const float2*)&sfh[base];
      float2 dnp = make_float2(INFV, INFV);
      if (rr < 127) dnp = *(const float2*)&su[rdn * NYg + cmin];
      float old0, old1, f0, f1, dn0, dn1;
      if (DC > 0) { old0 = oldp.x; old1 = oldp.y; f0 = fhp.x; f1 = fhp.y;
                    dn0 = dnp.x;  dn1 = dnp.y; }
      else        { old0 = oldp.y; old1 = oldp.x; f0 = fhp.y; f1 = fhp.x;
                    dn0 = dnp.y;  dn1 = dnp.x; }
      float rt1 = INFV;                       // ahead-col of second cell (old)
      if (lane != 63) rt1 = su[base + (DC > 0 ? 2 : -1)];
      // first cell: up=prev0, dn=dn0, lf=lfin, rt=old second cell (old value)
      const float n0 = cell_upd(old0, prev0, dn0, lfin, old1, f0, chg);
      // second cell: up=prev1, dn=dn1, lf=just-computed n0, rt=rt1
      const float n1 = cell_upd(old1, prev1, dn1, n0, rt1, f1, chg);
      float2 wr;
      if (DC > 0) { wr.x = n0; wr.y = n1; } else { wr.x = n1; wr.y = n0; }
      *(float2*)&su[base] = wr;
      prev0 = n0; prev1 = n1;
    }
  }
  return chg;
}

__global__ __launch_bounds__(64, 1) void eik_kernel(
    const float* __restrict__ vp, const float* __restrict__ vs,
    const float* __restrict__ station_loc, float* __restrict__ tab)
{
  __shared__ float su [NXg * NYg];   // 64 KiB travel-time field
  __shared__ float sfh[NXg * NYg];   // 64 KiB slowness f = 1/v (H = 1)

  const int lane = threadIdx.x;      // block = exactly one wave: no barriers
  const int blk  = blockIdx.x;
  const int st   = blk % NSTA;
  const int ph   = blk / NSTA;
  const float* __restrict__ v = ph ? vs : vp;

  // source cell: round-half-even like jnp.round (H = 1)
  const float sx = station_loc[st * 3 + 0];
  const float sy = station_loc[st * 3 + 1];
  int ix = (int)rintf(sx); ix = ix < 0 ? 0 : (ix > NXg - 1 ? NXg - 1 : ix);
  int iy = (int)rintf(sy); iy = iy < 0 ? 0 : (iy > NYg - 1 ? NYg - 1 : iy);
  const int src = ix * NYg + iy;

  // init: fh = 1/v (IEEE div, reference rounding), u = INF except source = 0
  for (int i = lane * 4; i < NXg * NYg; i += 64 * 4) {
    const float4 vv = *(const float4*)&v[i];
    float4 ff;
    ff.x = 1.0f / vv.x; ff.y = 1.0f / vv.y;
    ff.z = 1.0f / vv.z; ff.w = 1.0f / vv.w;
    *(float4*)&sfh[i] = ff;
    float4 uu = make_float4(INFV, INFV, INFV, INFV);
    if (src >= i && src < i + 4) (&uu.x)[src - i] = 0.0f;
    *(float4*)&su[i] = uu;
  }
  // single wave: LDS ops are program-ordered; no __syncthreads needed

  // fast-sweeping: rotate 4 directions; stop at first clean sweep (exact)
  for (int sp = 0; sp < MAXS; ++sp) {
    int chg;
    switch (sp & 3) {
      case 0:  chg = gsweep<+1, +1>(su, sfh, lane); break;
      case 1:  chg = gsweep<+1, -1>(su, sfh, lane); break;
      case 2:  chg = gsweep<-1, +1>(su, sfh, lane); break;
      default: chg = gsweep<-1, -1>(su, sfh, lane); break;
    }
    if (!__any(chg)) break;
  }

  // write result to global travel-time table
  float* __restrict__ To = tab + (size_t)(ph * NSTA + st) * NXg * NYg;
  for (int i = lane * 4; i < NXg * NYg; i += 64 * 4)
    *(float4*)&To[i] = *(const float4*)&su[i];
}

// ---------------------------------------------------------------------------
// Picks: bilinear interp + arrival times + per-(station,phase) MSE pieces.
// ---------------------------------------------------------------------------
__global__ void picks_kernel(
    const float* __restrict__ evloc, const float* __restrict__ evtime,
    const int* __restrict__ pst, const int* __restrict__ pph,
    const int* __restrict__ pev, const float* __restrict__ ptime,
    const float* __restrict__ tab, float* __restrict__ out,
    float* __restrict__ acc)
{
  __shared__ float lsse[2 * NSTA];
  __shared__ float lcnt[2 * NSTA];
  if (threadIdx.x < 2 * NSTA) { lsse[threadIdx.x] = 0.0f; lcnt[threadIdx.x] = 0.0f; }
  __syncthreads();

  int i = blockIdx.x * blockDim.x + threadIdx.x;
  if (i < NPICK) {
    int e = pev[i], s = pst[i], p = pph[i];
    float x = evloc[e * 3 + 0];
    float y = evloc[e * 3 + 1];
    int ir0 = (int)floorf(x); ir0 = ir0 < 0 ? 0 : (ir0 > NXg - 2 ? NXg - 2 : ir0);
    int iz0 = (int)floorf(y); iz0 = iz0 < 0 ? 0 : (iz0 > NYg - 2 ? NYg - 2 : iz0);
    float xc = fminf(fmaxf(x, 0.0f), (float)(NXg - 1));
    float yc = fminf(fmaxf(y, 0.0f), (float)(NYg - 1));
    float r0f = (float)ir0, z0f = (float)iz0;
    float r1 = r0f + 1.0f, z1 = z0f + 1.0f;

    const float* Tb = tab + (size_t)(p * NSTA + s) * NXg * NYg;
    float Q00 = Tb[ir0 * NYg + iz0];
    float Q01 = Tb[ir0 * NYg + iz0 + 1];
    float Q10 = Tb[(ir0 + 1) * NYg + iz0];
    float Q11 = Tb[(ir0 + 1) * NYg + iz0 + 1];
    float tt = Q00 * (r1 - xc) * (z1 - yc) + Q10 * (xc - r0f) * (z1 - yc)
             + Q01 * (r1 - xc) * (yc - z0f) + Q11 * (xc - r0f) * (yc - z0f);
    float at = evtime[e] + tt;
    out[i] = at;

    float dq = at - ptime[i];
    int g = s * 2 + p;
    atomicAdd(&lsse[g], dq * dq);
    atomicAdd(&lcnt[g], 1.0f);
  }
  __syncthreads();
  if (threadIdx.x < 2 * NSTA) {
    atomicAdd(&acc[threadIdx.x], lsse[threadIdx.x]);
    atomicAdd(&acc[2 * NSTA + threadIdx.x], lcnt[threadIdx.x]);
  }
}

__global__ void loss_kernel(const float* __restrict__ acc, float* __restrict__ out)
{
  int l = threadIdx.x;
  float v = 0.0f;
  if (l < 2 * NSTA) v = acc[l] / fmaxf(acc[2 * NSTA + l], 1.0f);
#pragma unroll
  for (int o = 32; o > 0; o >>= 1) v += __shfl_down(v, o, 64);
  if (l == 0) out[NPICK] = v;
}

// ---------------------------------------------------------------------------
extern "C" void kernel_launch(void* const* d_in, const int* in_sizes, int n_in,
                              void* d_out, int out_size, void* d_ws, size_t ws_size,
                              hipStream_t stream)
{
  const float* vp           = (const float*)d_in[0];
  const float* vs           = (const float*)d_in[1];
  const float* station_loc  = (const float*)d_in[2];
  const float* event_loc    = (const float*)d_in[3];
  const float* event_time   = (const float*)d_in[4];
  const int*   pick_station = (const int*)d_in[5];
  const int*   pick_phase   = (const int*)d_in[6];
  const int*   pick_event   = (const int*)d_in[7];
  const float* phase_time   = (const float*)d_in[8];

  float* out = (float*)d_out;
  float* acc = (float*)d_ws;          // [0,48): sse, [48,96): cnt
  float* tab = acc + 256;             // 2*24*128*128 f32 travel-time tables

  hipMemsetAsync(d_ws, 0, 96 * sizeof(float), stream);

  eik_kernel<<<2 * NSTA, 64, 0, stream>>>(vp, vs, station_loc, tab);

  picks_kernel<<<(NPICK + 255) / 256, 256, 0, stream>>>(
      event_loc, event_time, pick_station, pick_phase, pick_event, phase_time,
      tab, out, acc);

  loss_kernel<<<1, 64, 0, stream>>>(acc, out);
}

// Round 8
// 319.281 us; speedup vs baseline: 3.8652x; 3.8652x over previous
//
#include <hip/hip_runtime.h>

#define NXg   128
#define NYg   128
#define NSTA  24
#define NPICK 200000
#define INFV  1.0e6f
#define TS    8        // cells per thread per dim
#define TG    16       // tile grid is 16x16 tiles (256 threads)
#define MAXO  200      // safety cap; early exit is exact

// raw v_sqrt_f32 (~1 ulp) — skips the IEEE fixup chain
__device__ __forceinline__ float fsqrt_fast(float x) {
#if __has_builtin(__builtin_amdgcn_sqrtf)
  return __builtin_amdgcn_sqrtf(x);
#else
  float r; asm("v_sqrt_f32 %0, %1" : "=v"(r) : "v"(x)); return r;
#endif
}

// ---------------------------------------------------------------------------
// Eikonal: one block (256 threads) per (phase, station).
// Thread = 8x8 cell tile in registers; wave = 8x8 tile quadrant.
// Generation = up to 4 directional GS passes + halo exchange, with:
//  * ADAPTIVE PASS ORDER: first direction points away from the source
//    (fronts radiate outward), opposite direction last. The fixed point of
//    the monotone min-system is order-independent and the order is a
//    deterministic function of (wave, source) => exact.
//  * EARLY PASS-EXIT: a clean pass evaluated every cell against a fully
//    current field => local fixed point w.r.t. halos => remaining passes
//    are bitwise no-ops => stop.
//  * wave skip (r4): own + 4-neighbor flags quiet => identical inputs =>
//    deterministic operator => exact no-op.  Terminate on first globally
//    quiet generation.
// ---------------------------------------------------------------------------

template<int DR, int DC>
__device__ __forceinline__ void gs_pass(
    float (&u)[TS][TS], const float (&fh)[TS][TS], const float (&t2)[TS][TS],
    const float (&tpa)[TS], const float (&bta)[TS],
    const float (&lfa)[TS], const float (&rga)[TS], int &chg)
{
#pragma unroll
  for (int rr = 0; rr < TS; rr++) {
    const int r = (DR > 0) ? rr : (TS - 1 - rr);
#pragma unroll
    for (int cc = 0; cc < TS; cc++) {
      const int c = (DC > 0) ? cc : (TS - 1 - cc);
      const float up = (r == 0)      ? tpa[c] : u[r - 1][c];
      const float dn = (r == TS - 1) ? bta[c] : u[r + 1][c];
      const float lf = (c == 0)      ? lfa[r] : u[r][c - 1];
      const float rt = (c == TS - 1) ? rga[r] : u[r][c + 1];
      const float a  = fminf(up, dn);          // min x-neighbors (rows)
      const float b  = fminf(lf, rt);          // min y-neighbors (cols)
      const float dd = a - b;
      const float w  = fh[r][c];
      // no max(.,0) clamp: in the selected (two-sided) branch |dd|<w so the
      // sqrt arg > w^2 > 0; a NaN in the other branch is discarded by select.
      const float s  = __builtin_fmaf(-dd, dd, t2[r][c]);
      const float tw = 0.5f * ((a + b) + fsqrt_fast(s));
      const float on = fminf(a, b) + w;
      const float cand = (fabsf(dd) >= w) ? on : tw;
      const float old = u[r][c];
      chg |= (cand < old);
      u[r][c] = fminf(old, cand);
    }
  }
}

// run up to 4 passes in the given order with early exit after any clean pass
#define RUN4(R1,C1,R2,C2,R3,C3,R4,C4)                                   \
  {                                                                     \
    int c1 = 0;                                                         \
    gs_pass<R1, C1>(u, fh, t2, tpa, bta, lfa, rga, c1);                 \
    chg = c1;                                                           \
    if (__any(c1)) {                                                    \
      int c2 = 0;                                                       \
      gs_pass<R2, C2>(u, fh, t2, tpa, bta, lfa, rga, c2);               \
      chg |= c2;                                                        \
      if (__any(c2)) {                                                  \
        int c3 = 0;                                                     \
        gs_pass<R3, C3>(u, fh, t2, tpa, bta, lfa, rga, c3);             \
        chg |= c3;                                                      \
        if (__any(c3)) {                                                \
          int c4 = 0;                                                   \
          gs_pass<R4, C4>(u, fh, t2, tpa, bta, lfa, rga, c4);           \
          chg |= c4;                                                    \
        }                                                               \
      }                                                                 \
    }                                                                   \
  }

__global__ __launch_bounds__(256, 1) void eik_kernel(
    const float* __restrict__ vp, const float* __restrict__ vs,
    const float* __restrict__ station_loc, float* __restrict__ tab)
{
  // single-buffered tile-edge arrays: [tile][8]  (32 KiB total)
  __shared__ float eT[TG * TG][TS];
  __shared__ float eB[TG * TG][TS];
  __shared__ float eL[TG * TG][TS];
  __shared__ float eR[TG * TG][TS];
  // per-tile change flags with zero border ring (read/write regions are
  // separated by the mid-barrier)
  __shared__ int flg[TG + 2][TG + 2];

  const int t    = threadIdx.x;
  const int wv   = t >> 6;
  const int lane = t & 63;
  // wave <-> 8x8-tile quadrant mapping (skip granularity = wave)
  const int ti = (wv >> 1) * 8 + (lane >> 3);
  const int tj = (wv & 1) * 8 + (lane & 7);
  const int tid = ti * TG + tj;
  const int fi = ti + 1, fj = tj + 1;

  const int blk = blockIdx.x;
  const int st = blk % NSTA;
  const int ph = blk / NSTA;
  const float* __restrict__ v = ph ? vs : vp;

  // flags init: interior = 1 (everyone active at outer 0), border ring = 0
  for (int i = t; i < (TG + 2) * (TG + 2); i += 256) {
    const int r = i / (TG + 2), c = i % (TG + 2);
    (&flg[0][0])[i] = (r >= 1 && r <= TG && c >= 1 && c <= TG) ? 1 : 0;
  }

  // source cell: round-half-even like jnp.round (H = 1)
  const float sx = station_loc[st * 3 + 0];
  const float sy = station_loc[st * 3 + 1];
  int ix = (int)rintf(sx); ix = ix < 0 ? 0 : (ix > NXg - 1 ? NXg - 1 : ix);
  int iy = (int)rintf(sy); iy = iy < 0 ? 0 : (iy > NYg - 1 ? NYg - 1 : iy);

  // adaptive pass order: first direction points away from the source,
  // judged from this wave's 64x64 quadrant center (deterministic => exact)
  const int away_r = ((wv >> 1) * 64 + 32 > ix) ? 1 : 0;   // 1: +row is away
  const int away_c = ((wv & 1) * 64 + 32 > iy) ? 1 : 0;    // 1: +col is away
  const int order  = away_r * 2 + away_c;                  // 0..3

  const int r0 = ti * TS, c0 = tj * TS;
  float u[TS][TS], fh[TS][TS], t2[TS][TS];
#pragma unroll
  for (int r = 0; r < TS; r++) {
    const float4 v0 = *reinterpret_cast<const float4*>(&v[(r0 + r) * NYg + c0]);
    const float4 v1 = *reinterpret_cast<const float4*>(&v[(r0 + r) * NYg + c0 + 4]);
    fh[r][0] = 1.0f / v0.x; fh[r][1] = 1.0f / v0.y;
    fh[r][2] = 1.0f / v0.z; fh[r][3] = 1.0f / v0.w;
    fh[r][4] = 1.0f / v1.x; fh[r][5] = 1.0f / v1.y;
    fh[r][6] = 1.0f / v1.z; fh[r][7] = 1.0f / v1.w;
#pragma unroll
    for (int c = 0; c < TS; c++) {
      t2[r][c] = (2.0f * fh[r][c]) * fh[r][c];
      u[r][c] = ((r0 + r) == ix && (c0 + c) == iy) ? 0.0f : INFV;
    }
  }

  auto publish = [&]() {
    *reinterpret_cast<float4*>(&eT[tid][0]) = make_float4(u[0][0], u[0][1], u[0][2], u[0][3]);
    *reinterpret_cast<float4*>(&eT[tid][4]) = make_float4(u[0][4], u[0][5], u[0][6], u[0][7]);
    *reinterpret_cast<float4*>(&eB[tid][0]) = make_float4(u[7][0], u[7][1], u[7][2], u[7][3]);
    *reinterpret_cast<float4*>(&eB[tid][4]) = make_float4(u[7][4], u[7][5], u[7][6], u[7][7]);
    *reinterpret_cast<float4*>(&eL[tid][0]) = make_float4(u[0][0], u[1][0], u[2][0], u[3][0]);
    *reinterpret_cast<float4*>(&eL[tid][4]) = make_float4(u[4][0], u[5][0], u[6][0], u[7][0]);
    *reinterpret_cast<float4*>(&eR[tid][0]) = make_float4(u[0][7], u[1][7], u[2][7], u[3][7]);
    *reinterpret_cast<float4*>(&eR[tid][4]) = make_float4(u[4][7], u[5][7], u[6][7], u[7][7]);
  };

  publish();
  __syncthreads();

  for (int outer = 0; outer < MAXO; outer++) {
    // ---- read region: flags + halos (current values), compute ----
    const int nb = flg[fi][fj]
                 | flg[fi - 1][fj] | flg[fi + 1][fj]
                 | flg[fi][fj - 1] | flg[fi][fj + 1];
    int chg = 0;
    if (__any(nb)) {
      float tpa[TS], bta[TS], lfa[TS], rga[TS];
      {
        float4 h0 = make_float4(INFV, INFV, INFV, INFV), h1 = h0;
        if (ti > 0) {
          h0 = *reinterpret_cast<const float4*>(&eB[tid - TG][0]);
          h1 = *reinterpret_cast<const float4*>(&eB[tid - TG][4]);
        }
        tpa[0] = h0.x; tpa[1] = h0.y; tpa[2] = h0.z; tpa[3] = h0.w;
        tpa[4] = h1.x; tpa[5] = h1.y; tpa[6] = h1.z; tpa[7] = h1.w;
      }
      {
        float4 h0 = make_float4(INFV, INFV, INFV, INFV), h1 = h0;
        if (ti < TG - 1) {
          h0 = *reinterpret_cast<const float4*>(&eT[tid + TG][0]);
          h1 = *reinterpret_cast<const float4*>(&eT[tid + TG][4]);
        }
        bta[0] = h0.x; bta[1] = h0.y; bta[2] = h0.z; bta[3] = h0.w;
        bta[4] = h1.x; bta[5] = h1.y; bta[6] = h1.z; bta[7] = h1.w;
      }
      {
        float4 h0 = make_float4(INFV, INFV, INFV, INFV), h1 = h0;
        if (tj > 0) {
          h0 = *reinterpret_cast<const float4*>(&eR[tid - 1][0]);
          h1 = *reinterpret_cast<const float4*>(&eR[tid - 1][4]);
        }
        lfa[0] = h0.x; lfa[1] = h0.y; lfa[2] = h0.z; lfa[3] = h0.w;
        lfa[4] = h1.x; lfa[5] = h1.y; lfa[6] = h1.z; lfa[7] = h1.w;
      }
      {
        float4 h0 = make_float4(INFV, INFV, INFV, INFV), h1 = h0;
        if (tj < TG - 1) {
          h0 = *reinterpret_cast<const float4*>(&eL[tid + 1][0]);
          h1 = *reinterpret_cast<const float4*>(&eL[tid + 1][4]);
        }
        rga[0] = h0.x; rga[1] = h0.y; rga[2] = h0.z; rga[3] = h0.w;
        rga[4] = h1.x; rga[5] = h1.y; rga[6] = h1.z; rga[7] = h1.w;
      }

      // adaptive-order passes: away-direction first, opposite last
      switch (order) {
        case 3: RUN4(+1, +1, +1, -1, -1, +1, -1, -1); break;  // away = (+,+)
        case 2: RUN4(+1, -1, +1, +1, -1, -1, -1, +1); break;  // away = (+,-)
        case 1: RUN4(-1, +1, -1, -1, +1, +1, +1, -1); break;  // away = (-,+)
        default:RUN4(-1, -1, -1, +1, +1, -1, +1, +1); break;  // away = (-,-)
      }
    }

    __syncthreads();   // all reads of edges/flags done before any write

    // ---- write region: flag + edges (only if changed) ----
    flg[fi][fj] = chg;
    if (chg) publish();

    if (!__syncthreads_or(chg)) break;
  }

  float* __restrict__ To = tab + (size_t)(ph * NSTA + st) * NXg * NYg;
#pragma unroll
  for (int r = 0; r < TS; r++) {
    *reinterpret_cast<float4*>(&To[(r0 + r) * NYg + c0]) =
        make_float4(u[r][0], u[r][1], u[r][2], u[r][3]);
    *reinterpret_cast<float4*>(&To[(r0 + r) * NYg + c0 + 4]) =
        make_float4(u[r][4], u[r][5], u[r][6], u[r][7]);
  }
}

// ---------------------------------------------------------------------------
// Picks: bilinear interp + arrival times + per-(station,phase) MSE pieces.
// ---------------------------------------------------------------------------
__global__ void picks_kernel(
    const float* __restrict__ evloc, const float* __restrict__ evtime,
    const int* __restrict__ pst, const int* __restrict__ pph,
    const int* __restrict__ pev, const float* __restrict__ ptime,
    const float* __restrict__ tab, float* __restrict__ out,
    float* __restrict__ acc)
{
  __shared__ float lsse[2 * NSTA];
  __shared__ float lcnt[2 * NSTA];
  if (threadIdx.x < 2 * NSTA) { lsse[threadIdx.x] = 0.0f; lcnt[threadIdx.x] = 0.0f; }
  __syncthreads();

  int i = blockIdx.x * blockDim.x + threadIdx.x;
  if (i < NPICK) {
    int e = pev[i], s = pst[i], p = pph[i];
    float x = evloc[e * 3 + 0];
    float y = evloc[e * 3 + 1];
    int ir0 = (int)floorf(x); ir0 = ir0 < 0 ? 0 : (ir0 > NXg - 2 ? NXg - 2 : ir0);
    int iz0 = (int)floorf(y); iz0 = iz0 < 0 ? 0 : (iz0 > NYg - 2 ? NYg - 2 : iz0);
    float xc = fminf(fmaxf(x, 0.0f), (float)(NXg - 1));
    float yc = fminf(fmaxf(y, 0.0f), (float)(NYg - 1));
    float r0f = (float)ir0, z0f = (float)iz0;
    float r1 = r0f + 1.0f, z1 = z0f + 1.0f;

    const float* Tb = tab + (size_t)(p * NSTA + s) * NXg * NYg;
    float Q00 = Tb[ir0 * NYg + iz0];
    float Q01 = Tb[ir0 * NYg + iz0 + 1];
    float Q10 = Tb[(ir0 + 1) * NYg + iz0];
    float Q11 = Tb[(ir0 + 1) * NYg + iz0 + 1];
    float tt = Q00 * (r1 - xc) * (z1 - yc) + Q10 * (xc - r0f) * (z1 - yc)
             + Q01 * (r1 - xc) * (yc - z0f) + Q11 * (xc - r0f) * (yc - z0f);
    float at = evtime[e] + tt;
    out[i] = at;

    float dq = at - ptime[i];
    int g = s * 2 + p;
    atomicAdd(&lsse[g], dq * dq);
    atomicAdd(&lcnt[g], 1.0f);
  }
  __syncthreads();
  if (threadIdx.x < 2 * NSTA) {
    atomicAdd(&acc[threadIdx.x], lsse[threadIdx.x]);
    atomicAdd(&acc[2 * NSTA + threadIdx.x], lcnt[threadIdx.x]);
  }
}

__global__ void loss_kernel(const float* __restrict__ acc, float* __restrict__ out)
{
  int l = threadIdx.x;
  float v = 0.0f;
  if (l < 2 * NSTA) v = acc[l] / fmaxf(acc[2 * NSTA + l], 1.0f);
#pragma unroll
  for (int o = 32; o > 0; o >>= 1) v += __shfl_down(v, o, 64);
  if (l == 0) out[NPICK] = v;
}

// ---------------------------------------------------------------------------
extern "C" void kernel_launch(void* const* d_in, const int* in_sizes, int n_in,
                              void* d_out, int out_size, void* d_ws, size_t ws_size,
                              hipStream_t stream)
{
  const float* vp           = (const float*)d_in[0];
  const float* vs           = (const float*)d_in[1];
  const float* station_loc  = (const float*)d_in[2];
  const float* event_loc    = (const float*)d_in[3];
  const float* event_time   = (const float*)d_in[4];
  const int*   pick_station = (const int*)d_in[5];
  const int*   pick_phase   = (const int*)d_in[6];
  const int*   pick_event   = (const int*)d_in[7];
  const float* phase_time   = (const float*)d_in[8];

  float* out = (float*)d_out;
  float* acc = (float*)d_ws;          // [0,48): sse, [48,96): cnt
  float* tab = acc + 256;             // 2*24*128*128 f32 travel-time tables

  hipMemsetAsync(d_ws, 0, 96 * sizeof(float), stream);

  eik_kernel<<<2 * NSTA, 256, 0, stream>>>(vp, vs, station_loc, tab);

  picks_kernel<<<(NPICK + 255) / 256, 256, 0, stream>>>(
      event_loc, event_time, pick_station, pick_phase, pick_event, phase_time,
      tab, out, acc);

  loss_kernel<<<1, 64, 0, stream>>>(acc, out);
}

// Round 9
// 303.817 us; speedup vs baseline: 4.0619x; 1.0509x over previous
//
#include <hip/hip_runtime.h>

#define NXg   128
#define NYg   128
#define NSTA  24
#define NPICK 200000
#define INFV  1.0e6f
#define TS    8        // cells per thread per dim
#define TG    16       // tile grid is 16x16 tiles (256 threads)
#define MAXO  200      // safety cap; early exit is exact

// raw v_sqrt_f32 (~1 ulp) — skips the IEEE fixup chain
__device__ __forceinline__ float fsqrt_fast(float x) {
#if __has_builtin(__builtin_amdgcn_sqrtf)
  return __builtin_amdgcn_sqrtf(x);
#else
  float r; asm("v_sqrt_f32 %0, %1" : "=v"(r) : "v"(x)); return r;
#endif
}

// ---------------------------------------------------------------------------
// Eikonal: one block (256 threads) per (phase, station).
// Thread = 8x8 cell tile in registers; wave = 8x8 tile quadrant.
// Generation = up to 4 directional GS passes + halo exchange.
//  * ADAPTIVE ORDER, COMPACT: k-th pass direction = p ^ k where p points
//    away from the source (per-wave uniform). Runtime switch over the SAME
//    4 gs_pass instantiations (no code bloat — r8's regression was 16
//    inlined bodies thrashing the 32KB I$).
//  * EARLY PASS-EXIT: a clean pass evaluated every cell against the current
//    field => per-cell fixed point w.r.t. halos => ANY further directional
//    pass is a bitwise no-op (direction-independent certificate) => stop.
//  * wave skip (r4): own + 4-neighbor flags quiet => identical inputs =>
//    deterministic operator => exact no-op. Terminate on first globally
//    quiet generation.
// ---------------------------------------------------------------------------

template<int DR, int DC>
__device__ __forceinline__ void gs_pass(
    float (&u)[TS][TS], const float (&fh)[TS][TS], const float (&t2)[TS][TS],
    const float (&tpa)[TS], const float (&bta)[TS],
    const float (&lfa)[TS], const float (&rga)[TS], int &chg)
{
#pragma unroll
  for (int rr = 0; rr < TS; rr++) {
    const int r = (DR > 0) ? rr : (TS - 1 - rr);
#pragma unroll
    for (int cc = 0; cc < TS; cc++) {
      const int c = (DC > 0) ? cc : (TS - 1 - cc);
      const float up = (r == 0)      ? tpa[c] : u[r - 1][c];
      const float dn = (r == TS - 1) ? bta[c] : u[r + 1][c];
      const float lf = (c == 0)      ? lfa[r] : u[r][c - 1];
      const float rt = (c == TS - 1) ? rga[r] : u[r][c + 1];
      const float a  = fminf(up, dn);          // min x-neighbors (rows)
      const float b  = fminf(lf, rt);          // min y-neighbors (cols)
      const float dd = a - b;
      const float w  = fh[r][c];
      // no max(.,0) clamp: in the selected (two-sided) branch |dd|<w so the
      // sqrt arg > w^2 > 0; a NaN in the other branch is discarded by select.
      const float s  = __builtin_fmaf(-dd, dd, t2[r][c]);
      const float tw = 0.5f * ((a + b) + fsqrt_fast(s));
      const float on = fminf(a, b) + w;
      const float cand = (fabsf(dd) >= w) ? on : tw;
      const float old = u[r][c];
      chg |= (cand < old);
      u[r][c] = fminf(old, cand);
    }
  }
}

__global__ __launch_bounds__(256, 1) void eik_kernel(
    const float* __restrict__ vp, const float* __restrict__ vs,
    const float* __restrict__ station_loc, float* __restrict__ tab)
{
  // single-buffered tile-edge arrays: [tile][8]  (32 KiB total)
  __shared__ float eT[TG * TG][TS];
  __shared__ float eB[TG * TG][TS];
  __shared__ float eL[TG * TG][TS];
  __shared__ float eR[TG * TG][TS];
  // per-tile change flags with zero border ring (read/write regions are
  // separated by the mid-barrier)
  __shared__ int flg[TG + 2][TG + 2];

  const int t    = threadIdx.x;
  const int wv   = t >> 6;
  const int lane = t & 63;
  // wave <-> 8x8-tile quadrant mapping (skip granularity = wave)
  const int ti = (wv >> 1) * 8 + (lane >> 3);
  const int tj = (wv & 1) * 8 + (lane & 7);
  const int tid = ti * TG + tj;
  const int fi = ti + 1, fj = tj + 1;

  const int blk = blockIdx.x;
  const int st = blk % NSTA;
  const int ph = blk / NSTA;
  const float* __restrict__ v = ph ? vs : vp;

  // flags init: interior = 1 (everyone active at outer 0), border ring = 0
  for (int i = t; i < (TG + 2) * (TG + 2); i += 256) {
    const int r = i / (TG + 2), c = i % (TG + 2);
    (&flg[0][0])[i] = (r >= 1 && r <= TG && c >= 1 && c <= TG) ? 1 : 0;
  }

  // source cell: round-half-even like jnp.round (H = 1)
  const float sx = station_loc[st * 3 + 0];
  const float sy = station_loc[st * 3 + 1];
  int ix = (int)rintf(sx); ix = ix < 0 ? 0 : (ix > NXg - 1 ? NXg - 1 : ix);
  int iy = (int)rintf(sy); iy = iy < 0 ? 0 : (iy > NYg - 1 ? NYg - 1 : iy);

  // primary pass direction points away from the source, judged from this
  // wave's 64x64 quadrant center (wave-uniform, deterministic => exact).
  // dir code: 0=(+,+) 1=(+,-) 2=(-,+) 3=(-,-); k-th pass = p ^ k
  const int p = ((((wv >> 1) * 64 + 32) > ix) ? 0 : 2)
              | (((( wv & 1) * 64 + 32) > iy) ? 0 : 1);

  const int r0 = ti * TS, c0 = tj * TS;
  float u[TS][TS], fh[TS][TS], t2[TS][TS];
#pragma unroll
  for (int r = 0; r < TS; r++) {
    const float4 v0 = *reinterpret_cast<const float4*>(&v[(r0 + r) * NYg + c0]);
    const float4 v1 = *reinterpret_cast<const float4*>(&v[(r0 + r) * NYg + c0 + 4]);
    fh[r][0] = 1.0f / v0.x; fh[r][1] = 1.0f / v0.y;
    fh[r][2] = 1.0f / v0.z; fh[r][3] = 1.0f / v0.w;
    fh[r][4] = 1.0f / v1.x; fh[r][5] = 1.0f / v1.y;
    fh[r][6] = 1.0f / v1.z; fh[r][7] = 1.0f / v1.w;
#pragma unroll
    for (int c = 0; c < TS; c++) {
      t2[r][c] = (2.0f * fh[r][c]) * fh[r][c];
      u[r][c] = ((r0 + r) == ix && (c0 + c) == iy) ? 0.0f : INFV;
    }
  }

  auto publish = [&]() {
    *reinterpret_cast<float4*>(&eT[tid][0]) = make_float4(u[0][0], u[0][1], u[0][2], u[0][3]);
    *reinterpret_cast<float4*>(&eT[tid][4]) = make_float4(u[0][4], u[0][5], u[0][6], u[0][7]);
    *reinterpret_cast<float4*>(&eB[tid][0]) = make_float4(u[7][0], u[7][1], u[7][2], u[7][3]);
    *reinterpret_cast<float4*>(&eB[tid][4]) = make_float4(u[7][4], u[7][5], u[7][6], u[7][7]);
    *reinterpret_cast<float4*>(&eL[tid][0]) = make_float4(u[0][0], u[1][0], u[2][0], u[3][0]);
    *reinterpret_cast<float4*>(&eL[tid][4]) = make_float4(u[4][0], u[5][0], u[6][0], u[7][0]);
    *reinterpret_cast<float4*>(&eR[tid][0]) = make_float4(u[0][7], u[1][7], u[2][7], u[3][7]);
    *reinterpret_cast<float4*>(&eR[tid][4]) = make_float4(u[4][7], u[5][7], u[6][7], u[7][7]);
  };

  publish();
  __syncthreads();

  for (int outer = 0; outer < MAXO; outer++) {
    // ---- read region: flags + halos (current values), compute ----
    const int nb = flg[fi][fj]
                 | flg[fi - 1][fj] | flg[fi + 1][fj]
                 | flg[fi][fj - 1] | flg[fi][fj + 1];
    int chg = 0;
    if (__any(nb)) {
      float tpa[TS], bta[TS], lfa[TS], rga[TS];
      {
        float4 h0 = make_float4(INFV, INFV, INFV, INFV), h1 = h0;
        if (ti > 0) {
          h0 = *reinterpret_cast<const float4*>(&eB[tid - TG][0]);
          h1 = *reinterpret_cast<const float4*>(&eB[tid - TG][4]);
        }
        tpa[0] = h0.x; tpa[1] = h0.y; tpa[2] = h0.z; tpa[3] = h0.w;
        tpa[4] = h1.x; tpa[5] = h1.y; tpa[6] = h1.z; tpa[7] = h1.w;
      }
      {
        float4 h0 = make_float4(INFV, INFV, INFV, INFV), h1 = h0;
        if (ti < TG - 1) {
          h0 = *reinterpret_cast<const float4*>(&eT[tid + TG][0]);
          h1 = *reinterpret_cast<const float4*>(&eT[tid + TG][4]);
        }
        bta[0] = h0.x; bta[1] = h0.y; bta[2] = h0.z; bta[3] = h0.w;
        bta[4] = h1.x; bta[5] = h1.y; bta[6] = h1.z; bta[7] = h1.w;
      }
      {
        float4 h0 = make_float4(INFV, INFV, INFV, INFV), h1 = h0;
        if (tj > 0) {
          h0 = *reinterpret_cast<const float4*>(&eR[tid - 1][0]);
          h1 = *reinterpret_cast<const float4*>(&eR[tid - 1][4]);
        }
        lfa[0] = h0.x; lfa[1] = h0.y; lfa[2] = h0.z; lfa[3] = h0.w;
        lfa[4] = h1.x; lfa[5] = h1.y; lfa[6] = h1.z; lfa[7] = h1.w;
      }
      {
        float4 h0 = make_float4(INFV, INFV, INFV, INFV), h1 = h0;
        if (tj < TG - 1) {
          h0 = *reinterpret_cast<const float4*>(&eL[tid + 1][0]);
          h1 = *reinterpret_cast<const float4*>(&eL[tid + 1][4]);
        }
        rga[0] = h0.x; rga[1] = h0.y; rga[2] = h0.z; rga[3] = h0.w;
        rga[4] = h1.x; rga[5] = h1.y; rga[6] = h1.z; rga[7] = h1.w;
      }

      // adaptive-order passes via runtime dispatch over the same 4 bodies;
      // exit at first clean pass (direction-independent certificate)
      for (int k = 0; k < 4; ++k) {
        int ck = 0;
        switch (p ^ k) {
          case 0: gs_pass<+1, +1>(u, fh, t2, tpa, bta, lfa, rga, ck); break;
          case 1: gs_pass<+1, -1>(u, fh, t2, tpa, bta, lfa, rga, ck); break;
          case 2: gs_pass<-1, +1>(u, fh, t2, tpa, bta, lfa, rga, ck); break;
          default:gs_pass<-1, -1>(u, fh, t2, tpa, bta, lfa, rga, ck); break;
        }
        chg |= ck;
        if (!__any(ck)) break;
      }
    }

    __syncthreads();   // all reads of edges/flags done before any write

    // ---- write region: flag + edges (only if changed) ----
    flg[fi][fj] = chg;
    if (chg) publish();

    if (!__syncthreads_or(chg)) break;
  }

  float* __restrict__ To = tab + (size_t)(ph * NSTA + st) * NXg * NYg;
#pragma unroll
  for (int r = 0; r < TS; r++) {
    *reinterpret_cast<float4*>(&To[(r0 + r) * NYg + c0]) =
        make_float4(u[r][0], u[r][1], u[r][2], u[r][3]);
    *reinterpret_cast<float4*>(&To[(r0 + r) * NYg + c0 + 4]) =
        make_float4(u[r][4], u[r][5], u[r][6], u[r][7]);
  }
}

// ---------------------------------------------------------------------------
// Picks: bilinear interp + arrival times + per-(station,phase) MSE pieces.
// ---------------------------------------------------------------------------
__global__ void picks_kernel(
    const float* __restrict__ evloc, const float* __restrict__ evtime,
    const int* __restrict__ pst, const int* __restrict__ pph,
    const int* __restrict__ pev, const float* __restrict__ ptime,
    const float* __restrict__ tab, float* __restrict__ out,
    float* __restrict__ acc)
{
  __shared__ float lsse[2 * NSTA];
  __shared__ float lcnt[2 * NSTA];
  if (threadIdx.x < 2 * NSTA) { lsse[threadIdx.x] = 0.0f; lcnt[threadIdx.x] = 0.0f; }
  __syncthreads();

  int i = blockIdx.x * blockDim.x + threadIdx.x;
  if (i < NPICK) {
    int e = pev[i], s = pst[i], p = pph[i];
    float x = evloc[e * 3 + 0];
    float y = evloc[e * 3 + 1];
    int ir0 = (int)floorf(x); ir0 = ir0 < 0 ? 0 : (ir0 > NXg - 2 ? NXg - 2 : ir0);
    int iz0 = (int)floorf(y); iz0 = iz0 < 0 ? 0 : (iz0 > NYg - 2 ? NYg - 2 : iz0);
    float xc = fminf(fmaxf(x, 0.0f), (float)(NXg - 1));
    float yc = fminf(fmaxf(y, 0.0f), (float)(NYg - 1));
    float r0f = (float)ir0, z0f = (float)iz0;
    float r1 = r0f + 1.0f, z1 = z0f + 1.0f;

    const float* Tb = tab + (size_t)(p * NSTA + s) * NXg * NYg;
    float Q00 = Tb[ir0 * NYg + iz0];
    float Q01 = Tb[ir0 * NYg + iz0 + 1];
    float Q10 = Tb[(ir0 + 1) * NYg + iz0];
    float Q11 = Tb[(ir0 + 1) * NYg + iz0 + 1];
    float tt = Q00 * (r1 - xc) * (z1 - yc) + Q10 * (xc - r0f) * (z1 - yc)
             + Q01 * (r1 - xc) * (yc - z0f) + Q11 * (xc - r0f) * (yc - z0f);
    float at = evtime[e] + tt;
    out[i] = at;

    float dq = at - ptime[i];
    int g = s * 2 + p;
    atomicAdd(&lsse[g], dq * dq);
    atomicAdd(&lcnt[g], 1.0f);
  }
  __syncthreads();
  if (threadIdx.x < 2 * NSTA) {
    atomicAdd(&acc[threadIdx.x], lsse[threadIdx.x]);
    atomicAdd(&acc[2 * NSTA + threadIdx.x], lcnt[threadIdx.x]);
  }
}

__global__ void loss_kernel(const float* __restrict__ acc, float* __restrict__ out)
{
  int l = threadIdx.x;
  float v = 0.0f;
  if (l < 2 * NSTA) v = acc[l] / fmaxf(acc[2 * NSTA + l], 1.0f);
#pragma unroll
  for (int o = 32; o > 0; o >>= 1) v += __shfl_down(v, o, 64);
  if (l == 0) out[NPICK] = v;
}

// ---------------------------------------------------------------------------
extern "C" void kernel_launch(void* const* d_in, const int* in_sizes, int n_in,
                              void* d_out, int out_size, void* d_ws, size_t ws_size,
                              hipStream_t stream)
{
  const float* vp           = (const float*)d_in[0];
  const float* vs           = (const float*)d_in[1];
  const float* station_loc  = (const float*)d_in[2];
  const float* event_loc    = (const float*)d_in[3];
  const float* event_time   = (const float*)d_in[4];
  const int*   pick_station = (const int*)d_in[5];
  const int*   pick_phase   = (const int*)d_in[6];
  const int*   pick_event   = (const int*)d_in[7];
  const float* phase_time   = (const float*)d_in[8];

  float* out = (float*)d_out;
  float* acc = (float*)d_ws;          // [0,48): sse, [48,96): cnt
  float* tab = acc + 256;             // 2*24*128*128 f32 travel-time tables

  hipMemsetAsync(d_ws, 0, 96 * sizeof(float), stream);

  eik_kernel<<<2 * NSTA, 256, 0, stream>>>(vp, vs, station_loc, tab);

  picks_kernel<<<(NPICK + 255) / 256, 256, 0, stream>>>(
      event_loc, event_time, pick_station, pick_phase, pick_event, phase_time,
      tab, out, acc);

  loss_kernel<<<1, 64, 0, stream>>>(acc, out);
}

// Round 10
// 298.426 us; speedup vs baseline: 4.1353x; 1.0181x over previous
//
#include <hip/hip_runtime.h>

#define NXg   128
#define NYg   128
#define NSTA  24
#define NPICK 200000
#define INFV  1.0e6f
#define TS    8        // cells per thread per dim
#define TG    16       // tile grid is 16x16 tiles (256 threads)
#define RD    (TG + 2) // ring-padded tile-grid dim
#define MAXO  200      // safety cap; early exit is exact

// raw v_sqrt_f32 (~1 ulp) — skips the IEEE fixup chain
__device__ __forceinline__ float fsqrt_fast(float x) {
#if __has_builtin(__builtin_amdgcn_sqrtf)
  return __builtin_amdgcn_sqrtf(x);
#else
  float r; asm("v_sqrt_f32 %0, %1" : "=v"(r) : "v"(x)); return r;
#endif
}

// ---------------------------------------------------------------------------
// Eikonal: one block (256 threads) per (phase, station).
// Thread = 8x8 cell tile in registers; wave = 8x8 tile quadrant.
// SINGLE-BARRIER generation loop: edges + flags are double-buffered with an
// INFV/0 ring; EVERY tile publishes unconditionally into the write buffer
// each gen (asleep waves republish unchanged values at zero wall cost), so
// reads (buf rb) and writes (buf wb) never overlap and the only sync is the
// __syncthreads_or termination vote. Dataflow = r9 exactly (reads see end-of-
// previous-gen values), so results are bitwise identical.
// Payload per gen (r9): adaptive pass order (k-th dir = p ^ k, p away from
// source), early exit at first clean pass (direction-independent certificate),
// wave-level skip when own + 4-neighbor flags are quiet. All exits exact.
// ---------------------------------------------------------------------------

template<int DR, int DC>
__device__ __forceinline__ void gs_pass(
    float (&u)[TS][TS], const float (&fh)[TS][TS], const float (&t2)[TS][TS],
    const float (&tpa)[TS], const float (&bta)[TS],
    const float (&lfa)[TS], const float (&rga)[TS], int &chg)
{
#pragma unroll
  for (int rr = 0; rr < TS; rr++) {
    const int r = (DR > 0) ? rr : (TS - 1 - rr);
#pragma unroll
    for (int cc = 0; cc < TS; cc++) {
      const int c = (DC > 0) ? cc : (TS - 1 - cc);
      const float up = (r == 0)      ? tpa[c] : u[r - 1][c];
      const float dn = (r == TS - 1) ? bta[c] : u[r + 1][c];
      const float lf = (c == 0)      ? lfa[r] : u[r][c - 1];
      const float rt = (c == TS - 1) ? rga[r] : u[r][c + 1];
      const float a  = fminf(up, dn);          // min x-neighbors (rows)
      const float b  = fminf(lf, rt);          // min y-neighbors (cols)
      const float dd = a - b;
      const float w  = fh[r][c];
      // no max(.,0) clamp: in the selected (two-sided) branch |dd|<w so the
      // sqrt arg > w^2 > 0; a NaN in the other branch is discarded by select.
      const float s  = __builtin_fmaf(-dd, dd, t2[r][c]);
      const float tw = 0.5f * ((a + b) + fsqrt_fast(s));
      const float on = fminf(a, b) + w;
      const float cand = (fabsf(dd) >= w) ? on : tw;
      const float old = u[r][c];
      chg |= (cand < old);
      u[r][c] = fminf(old, cand);
    }
  }
}

__global__ __launch_bounds__(256, 1) void eik_kernel(
    const float* __restrict__ vp, const float* __restrict__ vs,
    const float* __restrict__ station_loc, float* __restrict__ tab)
{
  // double-buffered ring-padded tile-edge arrays (ring stays INFV forever)
  __shared__ float eT[2][RD * RD][TS];
  __shared__ float eB[2][RD * RD][TS];
  __shared__ float eL[2][RD * RD][TS];
  __shared__ float eR[2][RD * RD][TS];
  // double-buffered per-tile change flags (ring stays 0 forever)
  __shared__ int flg[2][RD][RD];

  const int t    = threadIdx.x;
  const int wv   = t >> 6;
  const int lane = t & 63;
  // wave <-> 8x8-tile quadrant mapping (skip granularity = wave)
  const int ti = (wv >> 1) * 8 + (lane >> 3);
  const int tj = (wv & 1) * 8 + (lane & 7);
  const int fi = ti + 1, fj = tj + 1;
  const int rid = fi * RD + fj;

  const int blk = blockIdx.x;
  const int st = blk % NSTA;
  const int ph = blk / NSTA;
  const float* __restrict__ v = ph ? vs : vp;

  // init: all edge entries INFV (ring is never rewritten), all flags 0
  for (int i = t; i < 2 * RD * RD; i += 256) {
    const int b = i / (RD * RD), rem = i % (RD * RD);
    const float4 inf4 = make_float4(INFV, INFV, INFV, INFV);
    *reinterpret_cast<float4*>(&eT[b][rem][0]) = inf4;
    *reinterpret_cast<float4*>(&eT[b][rem][4]) = inf4;
    *reinterpret_cast<float4*>(&eB[b][rem][0]) = inf4;
    *reinterpret_cast<float4*>(&eB[b][rem][4]) = inf4;
    *reinterpret_cast<float4*>(&eL[b][rem][0]) = inf4;
    *reinterpret_cast<float4*>(&eL[b][rem][4]) = inf4;
    *reinterpret_cast<float4*>(&eR[b][rem][0]) = inf4;
    *reinterpret_cast<float4*>(&eR[b][rem][4]) = inf4;
    flg[b][rem / RD][rem % RD] = 0;
  }

  // source cell: round-half-even like jnp.round (H = 1)
  const float sx = station_loc[st * 3 + 0];
  const float sy = station_loc[st * 3 + 1];
  int ix = (int)rintf(sx); ix = ix < 0 ? 0 : (ix > NXg - 1 ? NXg - 1 : ix);
  int iy = (int)rintf(sy); iy = iy < 0 ? 0 : (iy > NYg - 1 ? NYg - 1 : iy);

  // primary pass direction points away from the source (wave-uniform,
  // deterministic => exact). dir: 0=(+,+) 1=(+,-) 2=(-,+) 3=(-,-)
  const int p = ((((wv >> 1) * 64 + 32) > ix) ? 0 : 2)
              | (((( wv & 1) * 64 + 32) > iy) ? 0 : 1);

  const int r0 = ti * TS, c0 = tj * TS;
  float u[TS][TS], fh[TS][TS], t2[TS][TS];
#pragma unroll
  for (int r = 0; r < TS; r++) {
    const float4 v0 = *reinterpret_cast<const float4*>(&v[(r0 + r) * NYg + c0]);
    const float4 v1 = *reinterpret_cast<const float4*>(&v[(r0 + r) * NYg + c0 + 4]);
    fh[r][0] = 1.0f / v0.x; fh[r][1] = 1.0f / v0.y;
    fh[r][2] = 1.0f / v0.z; fh[r][3] = 1.0f / v0.w;
    fh[r][4] = 1.0f / v1.x; fh[r][5] = 1.0f / v1.y;
    fh[r][6] = 1.0f / v1.z; fh[r][7] = 1.0f / v1.w;
#pragma unroll
    for (int c = 0; c < TS; c++) {
      t2[r][c] = (2.0f * fh[r][c]) * fh[r][c];
      u[r][c] = ((r0 + r) == ix && (c0 + c) == iy) ? 0.0f : INFV;
    }
  }

  auto publish = [&](int pb) {
    *reinterpret_cast<float4*>(&eT[pb][rid][0]) = make_float4(u[0][0], u[0][1], u[0][2], u[0][3]);
    *reinterpret_cast<float4*>(&eT[pb][rid][4]) = make_float4(u[0][4], u[0][5], u[0][6], u[0][7]);
    *reinterpret_cast<float4*>(&eB[pb][rid][0]) = make_float4(u[7][0], u[7][1], u[7][2], u[7][3]);
    *reinterpret_cast<float4*>(&eB[pb][rid][4]) = make_float4(u[7][4], u[7][5], u[7][6], u[7][7]);
    *reinterpret_cast<float4*>(&eL[pb][rid][0]) = make_float4(u[0][0], u[1][0], u[2][0], u[3][0]);
    *reinterpret_cast<float4*>(&eL[pb][rid][4]) = make_float4(u[4][0], u[5][0], u[6][0], u[7][0]);
    *reinterpret_cast<float4*>(&eR[pb][rid][0]) = make_float4(u[0][7], u[1][7], u[2][7], u[3][7]);
    *reinterpret_cast<float4*>(&eR[pb][rid][4]) = make_float4(u[4][7], u[5][7], u[6][7], u[7][7]);
  };

  // gen 0 reads buffer 0
  publish(0);
  flg[0][fi][fj] = 1;
  __syncthreads();

  for (int outer = 0; outer < MAXO; outer++) {
    const int rb = outer & 1;
    const int wb = 1 - rb;

    // ---- read phase (buffer rb) ----
    const int nb = flg[rb][fi][fj]
                 | flg[rb][fi - 1][fj] | flg[rb][fi + 1][fj]
                 | flg[rb][fi][fj - 1] | flg[rb][fi][fj + 1];
    int chg = 0;
    if (__any(nb)) {
      float tpa[TS], bta[TS], lfa[TS], rga[TS];
      {
        const float4 h0 = *reinterpret_cast<const float4*>(&eB[rb][rid - RD][0]);
        const float4 h1 = *reinterpret_cast<const float4*>(&eB[rb][rid - RD][4]);
        tpa[0] = h0.x; tpa[1] = h0.y; tpa[2] = h0.z; tpa[3] = h0.w;
        tpa[4] = h1.x; tpa[5] = h1.y; tpa[6] = h1.z; tpa[7] = h1.w;
      }
      {
        const float4 h0 = *reinterpret_cast<const float4*>(&eT[rb][rid + RD][0]);
        const float4 h1 = *reinterpret_cast<const float4*>(&eT[rb][rid + RD][4]);
        bta[0] = h0.x; bta[1] = h0.y; bta[2] = h0.z; bta[3] = h0.w;
        bta[4] = h1.x; bta[5] = h1.y; bta[6] = h1.z; bta[7] = h1.w;
      }
      {
        const float4 h0 = *reinterpret_cast<const float4*>(&eR[rb][rid - 1][0]);
        const float4 h1 = *reinterpret_cast<const float4*>(&eR[rb][rid - 1][4]);
        lfa[0] = h0.x; lfa[1] = h0.y; lfa[2] = h0.z; lfa[3] = h0.w;
        lfa[4] = h1.x; lfa[5] = h1.y; lfa[6] = h1.z; lfa[7] = h1.w;
      }
      {
        const float4 h0 = *reinterpret_cast<const float4*>(&eL[rb][rid + 1][0]);
        const float4 h1 = *reinterpret_cast<const float4*>(&eL[rb][rid + 1][4]);
        rga[0] = h0.x; rga[1] = h0.y; rga[2] = h0.z; rga[3] = h0.w;
        rga[4] = h1.x; rga[5] = h1.y; rga[6] = h1.z; rga[7] = h1.w;
      }

      // adaptive-order passes over the same 4 instantiations (no I$ bloat);
      // exit at first clean pass (direction-independent certificate)
      for (int k = 0; k < 4; ++k) {
        int ck = 0;
        switch (p ^ k) {
          case 0: gs_pass<+1, +1>(u, fh, t2, tpa, bta, lfa, rga, ck); break;
          case 1: gs_pass<+1, -1>(u, fh, t2, tpa, bta, lfa, rga, ck); break;
          case 2: gs_pass<-1, +1>(u, fh, t2, tpa, bta, lfa, rga, ck); break;
          default:gs_pass<-1, -1>(u, fh, t2, tpa, bta, lfa, rga, ck); break;
        }
        chg |= ck;
        if (!__any(ck)) break;
      }
    }

    // ---- write phase (buffer wb, disjoint from rb: no mid-barrier) ----
    publish(wb);
    flg[wb][fi][fj] = chg;

    if (!__syncthreads_or(chg)) break;
  }

  float* __restrict__ To = tab + (size_t)(ph * NSTA + st) * NXg * NYg;
#pragma unroll
  for (int r = 0; r < TS; r++) {
    *reinterpret_cast<float4*>(&To[(r0 + r) * NYg + c0]) =
        make_float4(u[r][0], u[r][1], u[r][2], u[r][3]);
    *reinterpret_cast<float4*>(&To[(r0 + r) * NYg + c0 + 4]) =
        make_float4(u[r][4], u[r][5], u[r][6], u[r][7]);
  }
}

// ---------------------------------------------------------------------------
// Picks: bilinear interp + arrival times + per-(station,phase) MSE pieces.
// ---------------------------------------------------------------------------
__global__ void picks_kernel(
    const float* __restrict__ evloc, const float* __restrict__ evtime,
    const int* __restrict__ pst, const int* __restrict__ pph,
    const int* __restrict__ pev, const float* __restrict__ ptime,
    const float* __restrict__ tab, float* __restrict__ out,
    float* __restrict__ acc)
{
  __shared__ float lsse[2 * NSTA];
  __shared__ float lcnt[2 * NSTA];
  if (threadIdx.x < 2 * NSTA) { lsse[threadIdx.x] = 0.0f; lcnt[threadIdx.x] = 0.0f; }
  __syncthreads();

  int i = blockIdx.x * blockDim.x + threadIdx.x;
  if (i < NPICK) {
    int e = pev[i], s = pst[i], p = pph[i];
    float x = evloc[e * 3 + 0];
    float y = evloc[e * 3 + 1];
    int ir0 = (int)floorf(x); ir0 = ir0 < 0 ? 0 : (ir0 > NXg - 2 ? NXg - 2 : ir0);
    int iz0 = (int)floorf(y); iz0 = iz0 < 0 ? 0 : (iz0 > NYg - 2 ? NYg - 2 : iz0);
    float xc = fminf(fmaxf(x, 0.0f), (float)(NXg - 1));
    float yc = fminf(fmaxf(y, 0.0f), (float)(NYg - 1));
    float r0f = (float)ir0, z0f = (float)iz0;
    float r1 = r0f + 1.0f, z1 = z0f + 1.0f;

    const float* Tb = tab + (size_t)(p * NSTA + s) * NXg * NYg;
    float Q00 = Tb[ir0 * NYg + iz0];
    float Q01 = Tb[ir0 * NYg + iz0 + 1];
    float Q10 = Tb[(ir0 + 1) * NYg + iz0];
    float Q11 = Tb[(ir0 + 1) * NYg + iz0 + 1];
    float tt = Q00 * (r1 - xc) * (z1 - yc) + Q10 * (xc - r0f) * (z1 - yc)
             + Q01 * (r1 - xc) * (yc - z0f) + Q11 * (xc - r0f) * (yc - z0f);
    float at = evtime[e] + tt;
    out[i] = at;

    float dq = at - ptime[i];
    int g = s * 2 + p;
    atomicAdd(&lsse[g], dq * dq);
    atomicAdd(&lcnt[g], 1.0f);
  }
  __syncthreads();
  if (threadIdx.x < 2 * NSTA) {
    atomicAdd(&acc[threadIdx.x], lsse[threadIdx.x]);
    atomicAdd(&acc[2 * NSTA + threadIdx.x], lcnt[threadIdx.x]);
  }
}

__global__ void loss_kernel(const float* __restrict__ acc, float* __restrict__ out)
{
  int l = threadIdx.x;
  float v = 0.0f;
  if (l < 2 * NSTA) v = acc[l] / fmaxf(acc[2 * NSTA + l], 1.0f);
#pragma unroll
  for (int o = 32; o > 0; o >>= 1) v += __shfl_down(v, o, 64);
  if (l == 0) out[NPICK] = v;
}

// ---------------------------------------------------------------------------
extern "C" void kernel_launch(void* const* d_in, const int* in_sizes, int n_in,
                              void* d_out, int out_size, void* d_ws, size_t ws_size,
                              hipStream_t stream)
{
  const float* vp           = (const float*)d_in[0];
  const float* vs           = (const float*)d_in[1];
  const float* station_loc  = (const float*)d_in[2];
  const float* event_loc    = (const float*)d_in[3];
  const float* event_time   = (const float*)d_in[4];
  const int*   pick_station = (const int*)d_in[5];
  const int*   pick_phase   = (const int*)d_in[6];
  const int*   pick_event   = (const int*)d_in[7];
  const float* phase_time   = (const float*)d_in[8];

  float* out = (float*)d_out;
  float* acc = (float*)d_ws;          // [0,48): sse, [48,96): cnt
  float* tab = acc + 256;             // 2*24*128*128 f32 travel-time tables

  hipMemsetAsync(d_ws, 0, 96 * sizeof(float), stream);

  eik_kernel<<<2 * NSTA, 256, 0, stream>>>(vp, vs, station_loc, tab);

  picks_kernel<<<(NPICK + 255) / 256, 256, 0, stream>>>(
      event_loc, event_time, pick_station, pick_phase, pick_event, phase_time,
      tab, out, acc);

  loss_kernel<<<1, 64, 0, stream>>>(acc, out);
}